// Round 7
// baseline (304.226 us; speedup 1.0000x reference)
//
#include <hip/hip_runtime.h>
#include <hip/hip_bf16.h>
#include <cstdint>
#include <cstddef>

typedef __bf16 bf16x8 __attribute__((ext_vector_type(8)));
typedef float f32x4 __attribute__((ext_vector_type(4)));
typedef unsigned short u16;

#define SEQ 2048
#define NH 16
#define HD 128
#define DMODEL 2048
#define NQKV 6144
#define NB 32     // seq blocks (2048/64)
#define KSEL 512  // top-k blocks per head

__device__ __forceinline__ u16 f2bf(float f) {
  unsigned u = __float_as_uint(f);
  u += 0x7fffu + ((u >> 16) & 1u);  // round-to-nearest-even
  return (u16)(u >> 16);
}
__device__ __forceinline__ float bf2f(u16 b) {
  return __uint_as_float(((unsigned)b) << 16);
}

// Async global->LDS, 16B per lane. LDS dest = wave-uniform base + lane*16.
__device__ __forceinline__ void async_copy16(const void* g, void* l) {
  __builtin_amdgcn_global_load_lds(
      (__attribute__((address_space(1))) void*)(unsigned long long)g,
      (__attribute__((address_space(3))) void*)(unsigned)(unsigned long long)l,
      16, 0, 0);
}

// ---------------- fused pre-pass v3 ----------------
// bid 0..15: mask (serial rank-count, FIRST so it hides under BW work)
// bid 16..31: RoPE cos/sin table (2048 x 64 float2, accurate sincosf)
// bid 32..1055: convert hidden fp32->bf16
// bid 1056..3103: weight transposes (2 tiles/block, ushort4 writes)
__global__ __launch_bounds__(256) void pre_kernel(
    const float* __restrict__ hidden, const float* __restrict__ qw,
    const float* __restrict__ kw, const float* __restrict__ vw,
    const float* __restrict__ ow, const float* __restrict__ sp,
    u16* __restrict__ Xb, u16* __restrict__ Wqkvt, u16* __restrict__ Wot,
    int* __restrict__ sel_cnt, int* __restrict__ sel_idx, unsigned* __restrict__ sel_mask,
    float2* __restrict__ sctab) {
  __shared__ __align__(16) char smem[64 * 65 * 4];
  int bid = blockIdx.x, t = threadIdx.x;
  if (bid < 16) {  // mask: per-head top-512 by rank counting
    int h = bid;
    float* vals = (float*)smem;
    unsigned char* selb = (unsigned char*)(smem + 4096);
    for (int i = 0; i < 4; ++i) vals[t + i * 256] = sp[h * 1024 + t + i * 256];
    __syncthreads();
    for (int i = 0; i < 4; ++i) {
      float v = vals[t + i * 256];
      int cnt = 0;
      for (int j = 0; j < 1024; ++j) cnt += vals[j] > v ? 1 : 0;
      selb[t + i * 256] = (cnt < (KSEL - 1)) ? 1 : 0;  // rank<511 <=> strictly > thresh
    }
    __syncthreads();
    if (t < NB) {
      int n = 0; unsigned m = 0;
      for (int kb = 0; kb < NB; ++kb) {
        if (selb[t * NB + kb]) { sel_idx[(h * NB + t) * NB + n] = kb; ++n; m |= 1u << kb; }
      }
      sel_cnt[h * NB + t] = n;
      sel_mask[h * NB + t] = m;
    }
    return;
  }
  if (bid < 32) {  // cos/sin table: same powf/sincosf numerics as the old prep
    int b = bid - 16;  // 128 s-rows per block
    for (int i = 0; i < 32; ++i) {
      int idx = i * 256 + t;
      int s = b * 128 + (idx >> 6), j = idx & 63;
      float inv = powf(10000.0f, -(float)j / 64.0f);
      float sn, cs;
      sincosf((float)s * inv, &sn, &cs);
      sctab[s * 64 + j] = make_float2(cs, sn);
    }
    return;
  }
  if (bid < 1056) {  // convert: 2048x2048 fp32 -> bf16, 4 independent float4/thread
    int base = (bid - 32) * 1024 + t;
    float4 v0 = ((const float4*)hidden)[base];
    float4 v1 = ((const float4*)hidden)[base + 256];
    float4 v2 = ((const float4*)hidden)[base + 512];
    float4 v3 = ((const float4*)hidden)[base + 768];
    ((ushort4*)Xb)[base]       = make_ushort4(f2bf(v0.x), f2bf(v0.y), f2bf(v0.z), f2bf(v0.w));
    ((ushort4*)Xb)[base + 256] = make_ushort4(f2bf(v1.x), f2bf(v1.y), f2bf(v1.z), f2bf(v1.w));
    ((ushort4*)Xb)[base + 512] = make_ushort4(f2bf(v2.x), f2bf(v2.y), f2bf(v2.z), f2bf(v2.w));
    ((ushort4*)Xb)[base + 768] = make_ushort4(f2bf(v3.x), f2bf(v3.y), f2bf(v3.z), f2bf(v3.w));
    return;
  }
  // transpose+convert: 2 64x64 tiles per block
  float(*tile)[65] = (float(*)[65])smem;  // pad 65: both phases <=2-way bank alias
  for (int ti = 0; ti < 2; ++ti) {
    int tidx = (bid - 1056) * 2 + ti;  // 0..4095
    int wsel = tidx >> 10, rem = tidx & 1023, bx = rem & 31, by = rem >> 5;
    const float* in = (wsel == 0) ? qw : (wsel == 1) ? kw : (wsel == 2) ? vw : ow;
    u16* out = (wsel == 3) ? Wot : Wqkvt + (size_t)wsel * DMODEL * 2048;
    int c0 = bx * 64, r0 = by * 64;
    if (ti) __syncthreads();  // tile reuse fence
#pragma unroll
    for (int i = 0; i < 4; ++i) {  // read: float4-coalesced
      int chunk = i * 256 + t, r = chunk >> 4, c4 = chunk & 15;
      float4 v = *(const float4*)(in + (size_t)(r0 + r) * 2048 + c0 + c4 * 4);
      tile[r][c4 * 4 + 0] = v.x; tile[r][c4 * 4 + 1] = v.y;
      tile[r][c4 * 4 + 2] = v.z; tile[r][c4 * 4 + 3] = v.w;
    }
    __syncthreads();
#pragma unroll
    for (int i = 0; i < 4; ++i) {  // write: ushort4-coalesced
      int item = i * 256 + t, cc = item >> 4, rr4 = item & 15;
      ushort4 o = make_ushort4(f2bf(tile[rr4 * 4 + 0][cc]), f2bf(tile[rr4 * 4 + 1][cc]),
                               f2bf(tile[rr4 * 4 + 2][cc]), f2bf(tile[rr4 * 4 + 3][cc]));
      *(ushort4*)(out + (size_t)(c0 + cc) * 2048 + r0 + rr4 * 4) = o;
    }
  }
}

// ---------------- bf16 GEMM: C[m][n] = sum_k A[m][k] * Bt[n][k] ----------------
// m97 structure: 128x128 tile, BK=64, global_load_lds width=16, XOR-swizzled LDS.
// Wave n-tile map INTERLEAVED: ntoff = (w&1)*32 + (nt&1)*16 + (nt>>1)*64, so the
// RoPE pair (d, d+64) sits in the same thread (nt <-> nt+2) for MODE 2.
// MODE 0: plain fp32 store. MODE 1: fp32 atomicAdd (split-K via blockIdx.z).
// MODE 2: fused QKV epilogue -> RoPE'd Qh/Kh, transposed Vt, Vbsum. No C write.
template <int MODE>
__global__ __launch_bounds__(256, 2) void gemm_bt_kernel(
    const u16* __restrict__ A, const u16* __restrict__ Bt, void* __restrict__ Cout,
    int M, int N, int K, const float2* __restrict__ sctab,
    u16* __restrict__ Qh, u16* __restrict__ Kh, u16* __restrict__ Vt,
    float* __restrict__ Vbsum) {
  __shared__ __align__(16) u16 As[8192];  // 128 rows x 64 elems, swizzled
  __shared__ __align__(16) u16 Bs[8192];
  const int t = threadIdx.x;
  const int lane = t & 63, w = t >> 6;
  const int wm = (w >> 1) * 64;
  const int quad = lane >> 4, l16 = lane & 15;
  const int m0 = blockIdx.y * 128, n0 = blockIdx.x * 128;
  const int ksplit = K / gridDim.z, kbeg = blockIdx.z * ksplit;

  f32x4 acc[4][4] = {};

  for (int kt = kbeg; kt < kbeg + ksplit; kt += 64) {
    __syncthreads();  // previous iter's frag reads done before restaging
#pragma unroll
    for (int j = 0; j < 4; ++j) {
      int sl = w * 256 + j * 64 + lane;
      int row = sl >> 3, c = (sl & 7) ^ (row & 7);
      const u16* ga = A + (size_t)(m0 + row) * K + kt + c * 8;
      const u16* gb = Bt + (size_t)(n0 + row) * K + kt + c * 8;
      async_copy16(ga, &As[(size_t)(w * 256 + j * 64) * 8]);
      async_copy16(gb, &Bs[(size_t)(w * 256 + j * 64) * 8]);
    }
    __syncthreads();  // vmcnt(0) drain -> tile visible
#pragma unroll
    for (int ks = 0; ks < 2; ++ks) {
      bf16x8 af[4], bfr[4];
#pragma unroll
      for (int mt = 0; mt < 4; ++mt) {
        int row = wm + mt * 16 + l16;
        af[mt] = *(const bf16x8*)(&As[(row * 8 + ((ks * 4 + quad) ^ (l16 & 7))) * 8]);
      }
#pragma unroll
      for (int nt = 0; nt < 4; ++nt) {
        int row = (w & 1) * 32 + (nt & 1) * 16 + (nt >> 1) * 64 + l16;
        bfr[nt] = *(const bf16x8*)(&Bs[(row * 8 + ((ks * 4 + quad) ^ (l16 & 7))) * 8]);
      }
#pragma unroll
      for (int mt = 0; mt < 4; ++mt)
#pragma unroll
        for (int nt = 0; nt < 4; ++nt)
          acc[mt][nt] = __builtin_amdgcn_mfma_f32_16x16x32_bf16(af[mt], bfr[nt], acc[mt][nt], 0, 0, 0);
    }
  }
  // C/D layout: col=lane&15, row=quad*4+reg (m89-verified)
  if (MODE < 2) {
#pragma unroll
    for (int mt = 0; mt < 4; ++mt)
#pragma unroll
      for (int nt = 0; nt < 4; ++nt) {
        int coff = n0 + (w & 1) * 32 + (nt & 1) * 16 + (nt >> 1) * 64 + l16;
#pragma unroll
        for (int p = 0; p < 4; ++p) {
          int row = m0 + wm + mt * 16 + quad * 4 + p;
          if (MODE == 0)
            ((float*)Cout)[(size_t)row * N + coff] = acc[mt][nt][p];
          else
            unsafeAtomicAdd(&((float*)Cout)[(size_t)row * N + coff], acc[mt][nt][p]);
        }
      }
    return;
  }
  // MODE 2: fused QKV epilogue. Each n-block = one head's full 128-d.
  int wsel = n0 >> 11;       // 0=Q, 1=K, 2=V
  int h = (n0 >> 7) & 15;
  if (wsel < 2) {
    u16* dst = wsel ? Kh : Qh;
#pragma unroll
    for (int mt = 0; mt < 4; ++mt)
#pragma unroll
      for (int p = 0; p < 4; ++p) {
        int s = m0 + wm + mt * 16 + quad * 4 + p;
        const float2* trow = sctab + s * 64;
        u16* drow = dst + ((size_t)h * SEQ + s) * HD;
#pragma unroll
        for (int nt = 0; nt < 2; ++nt) {
          int j = (w & 1) * 32 + nt * 16 + l16;  // d < 64; pair at d+64 is nt+2
          float2 cs = trow[j];
          float lo = acc[mt][nt][p], hi = acc[mt][nt + 2][p];
          drow[j]      = f2bf(lo * cs.x - hi * cs.y);
          drow[j + 64] = f2bf(hi * cs.x + lo * cs.y);
        }
      }
  } else {
    int sb = (m0 >> 6) + (wm >> 6);  // this wave's 64-row s-block
#pragma unroll
    for (int nt = 0; nt < 4; ++nt) {
      int d = (w & 1) * 32 + (nt & 1) * 16 + (nt >> 1) * 64 + l16;
      u16* vrow = Vt + ((size_t)h * HD + d) * SEQ;
      float bsum = 0.f;
#pragma unroll
      for (int mt = 0; mt < 4; ++mt)
#pragma unroll
        for (int p = 0; p < 4; ++p) {
          int s = m0 + wm + mt * 16 + quad * 4 + p;
          float v = acc[mt][nt][p];
          vrow[s] = f2bf(v);
          bsum += v;
        }
      bsum += __shfl_xor(bsum, 16, 64);  // reduce over quads -> sum of 64 s
      bsum += __shfl_xor(bsum, 32, 64);
      if (quad == 0) Vbsum[((size_t)h * NB + sb) * HD + d] = bsum;
    }
  }
}

// ---------------- block-sparse attention v5: kb-split, 16 waves/CU ----------------
// Fixed m=0 softmax (exact) => partials over disjoint kb subsets ADD linearly.
// Grid 1024: each (h,qb) handled by 2 WGs (si parity). LDS single-buffered
// K+V+pbuf = 40960 B exactly -> 4 blocks/CU = 16 waves/CU: the exposed staging
// latency of one block is covered by 3 others' compute (m114). Partial O/rs go
// to per-half fp32 buffers with PLAIN stores (no atomics, fully overwritten).
__global__ __launch_bounds__(256, 4) void attn_kernel(
    const u16* __restrict__ Qh, const u16* __restrict__ Kh, const u16* __restrict__ Vt,
    const int* __restrict__ sel_cnt, const int* __restrict__ sel_idx,
    float* __restrict__ O0, float* __restrict__ O1,
    float* __restrict__ rs0, float* __restrict__ rs1) {
  __shared__ __align__(16) u16 Ks[8192];       // 64 k-rows x 128 d (16 chunks), c^(r&15)
  __shared__ __align__(16) u16 Vs[8192];       // 128 d-rows x 64 s (8 chunks), c^(d&7)
  __shared__ __align__(16) u16 pbuf[4][1024];  // per-wave 16x64, chunk-swizzle c^(row&7)
  // Decode: 2 heads per XCD (bid&7 = XCD slot); halves of one (h,qb) are
  // bids b and b+512 (512 % 8 == 0 -> same XCD, L2-shared K/V).
  int bid = blockIdx.x;
  int xcd = bid & 7, i = bid >> 3;
  int half = i >> 6, j = i & 63;
  int h = xcd * 2 + (j >> 5);
  int qb = j & 31;
  int t = threadIdx.x, lane = t & 63, w = t >> 6;
  int quad = lane >> 4, l16 = lane & 15;
  int rowblk = h * NB + qb;
  int nsel = sel_cnt[rowblk];
  const int* selrow = sel_idx + rowblk * NB;

  auto stageK = [&](int kb) {
    const u16* kbase = Kh + ((size_t)h * SEQ + kb * 64) * HD;
#pragma unroll
    for (int jj = 0; jj < 4; ++jj) {
      int s = w * 256 + jj * 64 + lane;
      int r = s >> 4, c = (s & 15) ^ (r & 15);
      async_copy16(kbase + (size_t)r * HD + c * 8, &Ks[(w * 256 + jj * 64) * 8]);
    }
  };
  auto stageV = [&](int kb) {
    const u16* vbase = Vt + (size_t)h * HD * SEQ + kb * 64;
#pragma unroll
    for (int jj = 0; jj < 4; ++jj) {
      int s = w * 256 + jj * 64 + lane;
      int d = s >> 3, c = (s & 7) ^ (d & 7);
      async_copy16(vbase + (size_t)d * SEQ + c * 8, &Vs[(w * 256 + jj * 64) * 8]);
    }
  };

  // Q fragments: A-layout m=lane&15, k=quad*8+j (4 k-steps of 32)
  bf16x8 qf[4];
  {
    const u16* qbase = Qh + ((size_t)h * SEQ + qb * 64 + w * 16 + l16) * HD + quad * 8;
#pragma unroll
    for (int kk = 0; kk < 4; ++kk) qf[kk] = *(const bf16x8*)(qbase + kk * 32);
  }
  float rs[4] = {0.f, 0.f, 0.f, 0.f};  // lane-local sum of P (reduced in epilogue)
  f32x4 oacc[8] = {};
  const float scale = 0.08838834764831845f;  // 1/sqrt(128)
  u16* pb = pbuf[w];

  for (int si = half; si < nsel; si += 2) {
    int kb = selrow[si];
    __syncthreads();  // prev iter's Ks/Vs reads done before restage
    stageK(kb);
    stageV(kb);
    __syncthreads();  // vmcnt(0) drain per wave -> K,V ready (covered by 3 co-resident blocks)

    f32x4 sacc[4] = {};
#pragma unroll
    for (int kk = 0; kk < 4; ++kk) {
#pragma unroll
      for (int nt = 0; nt < 4; ++nt) {
        int row = nt * 16 + l16;
        bf16x8 bfr = *(const bf16x8*)(&Ks[(row * 16 + ((kk * 4 + quad) ^ l16)) * 8]);
        sacc[nt] = __builtin_amdgcn_mfma_f32_16x16x32_bf16(qf[kk], bfr, sacc[nt], 0, 0, 0);
      }
    }
    // P = exp(s*scale), bf16-rounded; C-layout -> pbuf rows; track row sums
#pragma unroll
    for (int nt = 0; nt < 4; ++nt) {
#pragma unroll
      for (int p = 0; p < 4; ++p) {
        float pv = __expf(sacc[nt][p] * scale);
        u16 pr = f2bf(pv);
        int row = quad * 4 + p, col = nt * 16 + l16;
        pb[row * 64 + (((col >> 3) ^ (row & 7)) << 3) + (col & 7)] = pr;
        rs[p] += bf2f(pr);  // l consistent with rounded P
      }
    }
    // same-wave LDS write->read fence (pbuf wave-private; no cross-wave barrier)
    asm volatile("s_waitcnt lgkmcnt(0)" ::: "memory");
#pragma unroll
    for (int ks2 = 0; ks2 < 2; ++ks2) {
      bf16x8 pf = *(const bf16x8*)(pb + l16 * 64 + (((ks2 * 4 + quad) ^ (l16 & 7)) << 3));
#pragma unroll
      for (int nt = 0; nt < 8; ++nt) {
        int d = nt * 16 + l16;
        bf16x8 vf = *(const bf16x8*)(&Vs[(d * 8 + ((ks2 * 4 + quad) ^ (d & 7))) * 8]);
        oacc[nt] = __builtin_amdgcn_mfma_f32_16x16x32_bf16(pf, vf, oacc[nt], 0, 0, 0);
      }
    }
  }
  // epilogue: reduce rs over 16 lanes of each quad-group; plain stores of partials
#pragma unroll
  for (int p = 0; p < 4; ++p)
#pragma unroll
    for (int off = 1; off < 16; off <<= 1)
      rs[p] += __shfl_xor(rs[p], off, 64);
  float* Ob = half ? O1 : O0;
  float* rsb = half ? rs1 : rs0;
#pragma unroll
  for (int p = 0; p < 4; ++p) {
    int row = qb * 64 + w * 16 + quad * 4 + p;
    if (l16 == 0) rsb[h * SEQ + row] = rs[p];
#pragma unroll
    for (int nt = 0; nt < 8; ++nt)
      Ob[(size_t)row * DMODEL + h * HD + nt * 16 + l16] = oacc[nt][p];
  }
}

// ---------------- combine: O0+O1+vcorr, normalize, write bf16 attnb ----------------
__global__ __launch_bounds__(256) void combine_kernel(
    const float* __restrict__ O0, const float* __restrict__ O1,
    const float* __restrict__ rs0, const float* __restrict__ rs1,
    const float* __restrict__ Vbsum, const int* __restrict__ sel_cnt,
    const unsigned* __restrict__ sel_mask, u16* __restrict__ attnb) {
  __shared__ float vcs[HD];
  __shared__ float rinv[64];
  int sb = blockIdx.x, h = blockIdx.y, t = threadIdx.x;
  int rowblk = h * NB + sb;
  unsigned smask = sel_mask[rowblk];
  float cntm = 64.0f * (float)(NB - sel_cnt[rowblk]);  // masked cols: exp(0)=1 each
  if (t < HD) {
    float c = 0.f;
    for (int kb = 0; kb < NB; ++kb)
      if (!((smask >> kb) & 1u)) c += Vbsum[((size_t)h * NB + kb) * HD + t];
    vcs[t] = c;
  } else if (t < HD + 64) {
    int s = sb * 64 + (t - HD);
    rinv[t - HD] = 1.0f / (rs0[h * SEQ + s] + rs1[h * SEQ + s] + cntm);
  }
  __syncthreads();
#pragma unroll
  for (int it = 0; it < 8; ++it) {  // 64 rows x 32 float4 = 2048 float4
    int idx = it * 256 + t;
    int sl = idx >> 5, d4 = idx & 31;
    size_t g = (size_t)(sb * 64 + sl) * DMODEL + h * HD + d4 * 4;
    float4 a = *(const float4*)(O0 + g);
    float4 b = *(const float4*)(O1 + g);
    float iv = rinv[sl];
    ushort4 o = make_ushort4(f2bf((a.x + b.x + vcs[d4 * 4 + 0]) * iv),
                             f2bf((a.y + b.y + vcs[d4 * 4 + 1]) * iv),
                             f2bf((a.z + b.z + vcs[d4 * 4 + 2]) * iv),
                             f2bf((a.w + b.w + vcs[d4 * 4 + 3]) * iv));
    *(ushort4*)(attnb + g) = o;
  }
}

extern "C" void kernel_launch(void* const* d_in, const int* in_sizes, int n_in,
                              void* d_out, int out_size, void* d_ws, size_t ws_size,
                              hipStream_t stream) {
  const float* hidden = (const float*)d_in[0];
  const float* q_w = (const float*)d_in[1];
  const float* k_w = (const float*)d_in[2];
  const float* v_w = (const float*)d_in[3];
  const float* o_w = (const float*)d_in[4];
  const float* sp  = (const float*)d_in[5];

  char* ws = (char*)d_ws;
  size_t off = 0;
  auto alloc = [&](size_t bytes) -> void* {
    void* p = ws + off;
    off += (bytes + 255) & ~(size_t)255;
    return p;
  };
  u16* Xb     = (u16*)alloc((size_t)SEQ * DMODEL * 2);          // 8 MB (reused as attnb)
  u16* Wqkvt  = (u16*)alloc((size_t)NQKV * DMODEL * 2);         // 24 MB (reused as O0)
  u16* Wot    = (u16*)alloc((size_t)DMODEL * DMODEL * 2);       // 8 MB
  u16* Qh     = (u16*)alloc((size_t)NH * SEQ * HD * 2);         // 8 MB
  u16* Kh     = (u16*)alloc((size_t)NH * SEQ * HD * 2);         // 8 MB
  u16* Vt     = (u16*)alloc((size_t)NH * HD * SEQ * 2);         // 8 MB
  float* Vbsum = (float*)alloc((size_t)NH * NB * HD * 4);       // 256 KB
  float2* sctab = (float2*)alloc((size_t)SEQ * 64 * 8);         // 1 MB cos/sin
  float* rs0   = (float*)alloc((size_t)NH * SEQ * 4);           // 128 KB
  float* rs1   = (float*)alloc((size_t)NH * SEQ * 4);           // 128 KB
  int* sel_cnt = (int*)alloc(NH * NB * 4);
  int* sel_idx = (int*)alloc(NH * NB * NB * 4);
  unsigned* sel_mask = (unsigned*)alloc(NH * NB * 4);
  u16* attnb = Xb;          // Xb dead after QKV GEMM; combine writes it
  float* O0 = (float*)Wqkvt;  // Wqkvt (24 MB) dead after QKV GEMM; O0 = 16 MB
  float* O1 = (float*)d_out;  // d_out free until proj; memset AFTER combine reads it

  pre_kernel<<<3104, 256, 0, stream>>>(hidden, q_w, k_w, v_w, o_w, sp,
                                       Xb, Wqkvt, Wot, sel_cnt, sel_idx, sel_mask, sctab);
  // QKV GEMM with fused RoPE/transpose/Vbsum epilogue
  gemm_bt_kernel<2><<<dim3(NQKV / 128, SEQ / 128, 1), 256, 0, stream>>>(
      Xb, Wqkvt, nullptr, SEQ, NQKV, DMODEL, sctab, Qh, Kh, Vt, Vbsum);
  // attention partials: 1024 blocks (kb parity split), plain stores, no atomics
  attn_kernel<<<1024, 256, 0, stream>>>(Qh, Kh, Vt, sel_cnt, sel_idx, O0, O1, rs0, rs1);
  combine_kernel<<<dim3(NB, NH), 256, 0, stream>>>(O0, O1, rs0, rs1, Vbsum,
                                                   sel_cnt, sel_mask, attnb);
  hipMemsetAsync(d_out, 0, (size_t)SEQ * DMODEL * 4, stream);  // split-K accum base
  // proj GEMM: split-K=2 -> 512 blocks, fp32 atomic accum
  gemm_bt_kernel<1><<<dim3(DMODEL / 128, SEQ / 128, 2), 256, 0, stream>>>(
      attnb, Wot, d_out, SEQ, DMODEL, DMODEL, nullptr, nullptr, nullptr, nullptr, nullptr);
}